// Round 4
// baseline (4558.326 us; speedup 1.0000x reference)
//
#include <hip/hip_runtime.h>
#include <stdint.h>

using u16 = unsigned short;
typedef unsigned int u32;
typedef __attribute__((ext_vector_type(4))) float f32x4;
typedef __attribute__((ext_vector_type(8))) short short8;

typedef const __attribute__((address_space(1))) u32* gas_ptr;
typedef __attribute__((address_space(3))) u32* las_ptr;

// ---------- bf16 helpers (bit-level, RNE) ----------
__device__ __forceinline__ u16 f2bf_u(float f) {
    u32 u = __builtin_bit_cast(u32, f);
    u32 r = 0x7fffu + ((u >> 16) & 1u);
    return (u16)((u + r) >> 16);
}
__device__ __forceinline__ float bfu2f(u16 h) {
    u32 u = ((u32)h) << 16;
    return __builtin_bit_cast(float, u);
}
__device__ __forceinline__ void split2(float v, u16& hi, u16& lo) {
    hi = f2bf_u(v);
    lo = f2bf_u(v - bfu2f(hi));   // exact residual, ~16 mantissa bits total
}

__device__ __forceinline__ void gload16(const void* g, void* l) {
    __builtin_amdgcn_global_load_lds((gas_ptr)g, (las_ptr)l, 16, 0, 0);
}

// ---------- GEMM-BT (both operands K-contiguous), 128x128 tile, BK=32 ----------
// SPLIT=true: C[row][col] = sum_k (Ahi*Bhi + Alo*Bhi + Ahi*Blo)  (3 products,
//   one K-pass: stage all 4 tiles per K-step, 48 MFMA per barrier-pair)
// SPLIT=false: plain Ahi*Bhi.
// K = length of this pass's K range; lda = row stride (elements) of A and B.
// K-chunking (GEMM1): launch 4x with K=4096, lda=16384, base ptrs offset by
// chunk*4096; partials carried in out0/out1 as bf16 hi/lo between launches.
// Working set per chunk = 128 MB < 256 MB L3 -> B re-streams are L3 hits.
// LDS chunk swizzle: slot (row, c) holds global 16B-chunk c ^ ((row>>1)&3),
// staged via pre-swizzled GLOBAL source (LDS dest linear, global_load_lds
// rule), read with matching XOR -> conflict-free ds_read_b128 (verified: 0).
// EPI 0 (GEMM1 chunks): mode 0: write split(acc);
//                       mode 1: write split(acc + prev);
//                       mode 2: v=acc+prev+aux[col]; relu; write split(v)
// EPI 1: v=acc+aux[col]; bf16 split scatter to [b][col][c] (b=row>>9,c=row&511)
// EPI 2: fp32 row-major write (scores; per-row scale applied in softmax)
// EPI 3: fp32 write with batch stride (preLN)
template<int EPI, bool SPLIT>
__global__ __launch_bounds__(256)
void gemm_bt(const u16* __restrict__ Ah, const u16* __restrict__ Al,
             const u16* __restrict__ Bh, const u16* __restrict__ Bl,
             int K, int lda, int N,
             const float* __restrict__ aux,
             void* __restrict__ out0, void* __restrict__ out1,
             int mode,
             size_t strideA, size_t strideB, size_t strideO)
{
    __shared__ __align__(16) u16 As0[128 * 32];
    __shared__ __align__(16) u16 Bs0[128 * 32];
    __shared__ __align__(16) u16 As1[SPLIT ? 128 * 32 : 8];
    __shared__ __align__(16) u16 Bs1[SPLIT ? 128 * 32 : 8];

    const int t = threadIdx.x;
    const int w = t >> 6;
    const int l = t & 63;

    // XCD-chunked bijective swizzle (all grids have nwg % 8 == 0)
    const int gx = gridDim.x;
    const int nwg = gx * gridDim.y;
    const int orig = blockIdx.y * gx + blockIdx.x;
    const int swz = (orig & 7) * (nwg >> 3) + (orig >> 3);
    const int brow = (swz / gx) * 128;
    const int bcol = (swz % gx) * 128;
    const int z = blockIdx.z;

    const u16* A0 = Ah + (size_t)z * strideA;
    const u16* A1 = SPLIT ? (Al + (size_t)z * strideA) : nullptr;
    const u16* B0 = Bh + (size_t)z * strideB;
    const u16* B1 = SPLIT ? (Bl + (size_t)z * strideB) : nullptr;

    // staging: lane l covers row l>>2 (of 16), LDS chunk l&3;
    // global chunk for that slot = (l&3) ^ ((row>>1)&3) = (l&3) ^ ((l>>3)&3)
    const int srow = l >> 2;
    const int sca = ((l & 3) ^ ((l >> 3) & 3)) * 8;

    f32x4 acc[4][4];
    const f32x4 zero = {0.f, 0.f, 0.f, 0.f};
#pragma unroll
    for (int i = 0; i < 4; ++i)
#pragma unroll
        for (int j = 0; j < 4; ++j) acc[i][j] = zero;

    const int wr = w >> 1;
    const int wc = w & 1;
    const int lr = l & 15;
    // frag read: row R = base + (l&15), want global chunk g = l>>4;
    // slot chunk = g ^ ((R>>1)&3) = (l>>4) ^ (((l&15)>>1)&3)
    const int cr = ((l >> 4) ^ ((l >> 1) & 3)) * 8;

    for (int kk = 0; kk < K; kk += 32) {
        __syncthreads();
#pragma unroll
        for (int c = 0; c < 2; ++c) {
            const int r = w * 32 + c * 16;   // wave-uniform LDS base row
            const size_t ga = (size_t)(brow + r + srow) * lda + (kk + sca);
            const size_t gb = (size_t)(bcol + r + srow) * lda + (kk + sca);
            gload16(A0 + ga, &As0[r * 32]);
            gload16(B0 + gb, &Bs0[r * 32]);
            if constexpr (SPLIT) {
                gload16(A1 + ga, &As1[r * 32]);
                gload16(B1 + gb, &Bs1[r * 32]);
            }
        }
        __syncthreads();
        short8 ah[4], bh[4], al[4], bl[4];
#pragma unroll
        for (int m = 0; m < 4; ++m) {
            const int ro = (wr * 64 + m * 16 + lr) * 32 + cr;
            ah[m] = *(const short8*)&As0[ro];
            if constexpr (SPLIT) al[m] = *(const short8*)&As1[ro];
        }
#pragma unroll
        for (int n = 0; n < 4; ++n) {
            const int ro = (wc * 64 + n * 16 + lr) * 32 + cr;
            bh[n] = *(const short8*)&Bs0[ro];
            if constexpr (SPLIT) bl[n] = *(const short8*)&Bs1[ro];
        }
#pragma unroll
        for (int m = 0; m < 4; ++m)
#pragma unroll
            for (int n = 0; n < 4; ++n)
                acc[m][n] = __builtin_amdgcn_mfma_f32_16x16x32_bf16(ah[m], bh[n], acc[m][n], 0, 0, 0);
        if constexpr (SPLIT) {
#pragma unroll
            for (int m = 0; m < 4; ++m)
#pragma unroll
                for (int n = 0; n < 4; ++n) {
                    acc[m][n] = __builtin_amdgcn_mfma_f32_16x16x32_bf16(al[m], bh[n], acc[m][n], 0, 0, 0);
                    acc[m][n] = __builtin_amdgcn_mfma_f32_16x16x32_bf16(ah[m], bl[n], acc[m][n], 0, 0, 0);
                }
        }
    }

#pragma unroll
    for (int m = 0; m < 4; ++m)
#pragma unroll
        for (int n = 0; n < 4; ++n)
#pragma unroll
            for (int j = 0; j < 4; ++j) {
                const int row = brow + wr * 64 + m * 16 + (l >> 4) * 4 + j;
                const int col = bcol + wc * 64 + n * 16 + (l & 15);
                float v = acc[m][n][j];
                if (EPI == 0) {
                    const size_t idx = (size_t)row * N + col;
                    if (mode > 0)
                        v += bfu2f(((const u16*)out0)[idx]) + bfu2f(((const u16*)out1)[idx]);
                    if (mode == 2) {
                        v += aux[col];
                        v = fmaxf(v, 0.f);
                    }
                    u16 hi, lo; split2(v, hi, lo);
                    ((u16*)out0)[idx] = hi;
                    ((u16*)out1)[idx] = lo;
                } else if (EPI == 1) {
                    v += aux[col];
                    const int bb = row >> 9, cc = row & 511;
                    const size_t idx = ((size_t)bb * N + col) * 512 + cc;
                    u16 hi, lo; split2(v, hi, lo);
                    ((u16*)out0)[idx] = hi;
                    ((u16*)out1)[idx] = lo;
                } else if (EPI == 2) {
                    ((float*)out0)[(size_t)row * N + col] = v;
                } else {
                    ((float*)out0)[(size_t)z * strideO + (size_t)row * N + col] = v;
                }
            }
}

// ---------- elementwise split fp32 -> (hi,lo) bf16 ----------
__global__ void split_k(const float* __restrict__ in, u16* __restrict__ hi,
                        u16* __restrict__ lo, size_t n4)
{
    size_t i = blockIdx.x * (size_t)blockDim.x + threadIdx.x;
    const size_t stride = (size_t)gridDim.x * blockDim.x;
    for (; i < n4; i += stride) {
        const float4 v = ((const float4*)in)[i];
        ushort4 h, l;
        split2(v.x, h.x, l.x);
        split2(v.y, h.y, l.y);
        split2(v.z, h.z, l.z);
        split2(v.w, h.w, l.w);
        ((ushort4*)hi)[i] = h;
        ((ushort4*)lo)[i] = l;
    }
}

// ---------- plain fp32 -> bf16 convert ----------
__global__ void conv_bf16_k(const float* __restrict__ in, u16* __restrict__ out, size_t n4)
{
    size_t i = blockIdx.x * (size_t)blockDim.x + threadIdx.x;
    const size_t stride = (size_t)gridDim.x * blockDim.x;
    for (; i < n4; i += stride) {
        const float4 v = ((const float4*)in)[i];
        ushort4 o;
        o.x = f2bf_u(v.x); o.y = f2bf_u(v.y); o.z = f2bf_u(v.z); o.w = f2bf_u(v.w);
        ((ushort4*)out)[i] = o;
    }
}

// ---------- x (B,512,4096) -> xt (B,4096,512) with bf16 hi/lo split ----------
__global__ void transpose_split_x(const float* __restrict__ x,
                                  u16* __restrict__ xt_hi, u16* __restrict__ xt_lo)
{
    __shared__ float tile[32][33];
    const int b = blockIdx.z;
    const int n0 = blockIdx.x * 32;
    const int c0 = blockIdx.y * 32;
    const int tx = threadIdx.x, ty = threadIdx.y;   // block (32,8)
#pragma unroll
    for (int k = 0; k < 4; ++k)
        tile[ty + 8 * k][tx] = x[((size_t)b * 512 + c0 + ty + 8 * k) * 4096 + n0 + tx];
    __syncthreads();
#pragma unroll
    for (int k = 0; k < 4; ++k) {
        const float v = tile[tx][ty + 8 * k];       // [c_local][n_local]
        u16 hi, lo; split2(v, hi, lo);
        const size_t idx = ((size_t)b * 4096 + n0 + ty + 8 * k) * 512 + c0 + tx;
        xt_hi[idx] = hi;
        xt_lo[idx] = lo;
    }
}

// ---------- scale vector: s[n] = exp(min(ls[n], log(100))) ----------
__global__ void scale_prep(const float* __restrict__ ls, float* __restrict__ s)
{
    const int i = blockIdx.x * blockDim.x + threadIdx.x;
    if (i < 4096) s[i] = expf(fminf(ls[i], 4.605170185988092f));
}

// ---------- row softmax of tempT (4096 cols), row-scale s[m], write bf16 P ----------
__global__ __launch_bounds__(256)
void softmax_rows(const float* __restrict__ T, const float* __restrict__ s, u16* __restrict__ P)
{
    const int m = blockIdx.x;
    const int t = threadIdx.x;
    const float sc = s[m];
    const float* row = T + (size_t)m * 4096;
    float v[16];
    float mx = -3.402823e38f;
#pragma unroll
    for (int i = 0; i < 16; ++i) {
        v[i] = row[t + 256 * i] * sc;
        mx = fmaxf(mx, v[i]);
    }
#pragma unroll
    for (int o = 32; o; o >>= 1) mx = fmaxf(mx, __shfl_xor(mx, o, 64));
    __shared__ float sm[4], ss[4];
    if ((t & 63) == 0) sm[t >> 6] = mx;
    __syncthreads();
    mx = fmaxf(fmaxf(sm[0], sm[1]), fmaxf(sm[2], sm[3]));
    float sum = 0.f;
#pragma unroll
    for (int i = 0; i < 16; ++i) {
        v[i] = expf(v[i] - mx);
        sum += v[i];
    }
#pragma unroll
    for (int o = 32; o; o >>= 1) sum += __shfl_xor(sum, o, 64);
    if ((t & 63) == 0) ss[t >> 6] = sum;
    __syncthreads();
    sum = (ss[0] + ss[1]) + (ss[2] + ss[3]);
    const float inv = 1.f / sum;
#pragma unroll
    for (int i = 0; i < 16; ++i)
        P[(size_t)m * 4096 + t + 256 * i] = f2bf_u(v[i] * inv);
}

// ---------- LayerNorm rows of 4096 ----------
__global__ __launch_bounds__(256)
void ln_rows(const float* __restrict__ X, const float* __restrict__ gw,
             const float* __restrict__ gb, float* __restrict__ out)
{
    const int r = blockIdx.x;
    const int t = threadIdx.x;
    const float* row = X + (size_t)r * 4096;
    float v[16];
    float s1 = 0.f, s2 = 0.f;
#pragma unroll
    for (int i = 0; i < 16; ++i) {
        v[i] = row[t + 256 * i];
        s1 += v[i];
        s2 += v[i] * v[i];
    }
#pragma unroll
    for (int o = 32; o; o >>= 1) {
        s1 += __shfl_xor(s1, o, 64);
        s2 += __shfl_xor(s2, o, 64);
    }
    __shared__ float m1[4], m2[4];
    if ((t & 63) == 0) { m1[t >> 6] = s1; m2[t >> 6] = s2; }
    __syncthreads();
    s1 = (m1[0] + m1[1]) + (m1[2] + m1[3]);
    s2 = (m2[0] + m2[1]) + (m2[2] + m2[3]);
    const float mu = s1 * (1.f / 4096.f);
    const float var = s2 * (1.f / 4096.f) - mu * mu;
    const float rs = rsqrtf(var + 1e-5f);
#pragma unroll
    for (int i = 0; i < 16; ++i) {
        const int n = t + 256 * i;
        out[(size_t)r * 4096 + n] = (v[i] - mu) * rs * gw[n] + gb[n];
    }
}

extern "C" void kernel_launch(void* const* d_in, const int* in_sizes, int n_in,
                              void* d_out, int out_size, void* d_ws, size_t ws_size,
                              hipStream_t stream)
{
    const float* x  = (const float*)d_in[0];
    const float* fe = (const float*)d_in[1];
    const float* w1 = (const float*)d_in[2];
    const float* b1 = (const float*)d_in[3];
    const float* w2 = (const float*)d_in[4];
    const float* b2 = (const float*)d_in[5];
    const float* ls = (const float*)d_in[6];
    const float* nw = (const float*)d_in[7];
    const float* nb = (const float*)d_in[8];
    float* out = (float*)d_out;
    char* ws = (char*)d_ws;

    if (ws_size < 637550592ull) return;

    // Workspace plan (stream-order lifetime reuse):
    u16*  fhi  = (u16*) (ws + 0ull);
    u16*  flo  = (u16*) (ws + 134217728ull);
    u16*  w1hi = (u16*) (ws + 268435456ull);
    u16*  w1lo = (u16*) (ws + 402653184ull);
    u16*  hhi  = (u16*) (ws + 536870912ull);
    u16*  hlo  = (u16*) (ws + 570425344ull);
    u16*  w2hi = (u16*) (ws + 0ull);           // fe region dead after GEMM1
    u16*  w2lo = (u16*) (ws + 33554432ull);
    u16*  fthi = (u16*) (ws + 67108864ull);
    u16*  ftlo = (u16*) (ws + 100663296ull);
    u16*  xthi = (u16*) (ws + 134217728ull);
    u16*  xtlo = (u16*) (ws + 167772160ull);
    u16*  xbf  = (u16*) (ws + 201326592ull);
    float* tt  = (float*)(ws + 234881024ull);   // one-batch scores, fp32
    u16*  pall = (u16*) (ws + 301989888ull);    // P bf16, all batches
    float* pre = (float*)(ws + 570425344ull);   // pre-LN fp32 (h dead)
    float* sv  = (float*)(ws + 637534208ull);

    // 1. split feature and fc1_w
    split_k<<<2048, 256, 0, stream>>>(fe, fhi, flo, (size_t)16777216);
    split_k<<<2048, 256, 0, stream>>>(w1, w1hi, w1lo, (size_t)16777216);

    // 2. GEMM1 K-chunked: 4 x (K=4096) passes; per-chunk working set = 128 MB
    //    (fits 256 MB L3 -> B re-streams are L3 hits, not HBM).
    //    Partials carried in hhi/hlo as bf16 hi+lo between launches.
    for (int c = 0; c < 4; ++c) {
        const int mode = (c == 0) ? 0 : (c == 3 ? 2 : 1);
        const int ko = c * 4096;
        gemm_bt<0, true><<<dim3(32, 32, 1), 256, 0, stream>>>(
            fhi + ko, flo + ko, w1hi + ko, w1lo + ko,
            4096, 16384, 4096, b1, hhi, hlo, mode, 0, 0, 0);
    }

    // 3. split fc2_w (fe region dead after GEMM1 in stream order)
    split_k<<<2048, 256, 0, stream>>>(w2, w2hi, w2lo, (size_t)4194304);

    // 4. GEMM2: feat = h @ fc2_w^T + b2, split scatter to ft[b][n][c]
    gemm_bt<1, true><<<dim3(32, 32, 1), 256, 0, stream>>>(hhi, hlo, w2hi, w2lo,
        4096, 4096, 4096, b2, fthi, ftlo, 0, 0, 0, 0);

    // 5. x transforms + scale vector
    transpose_split_x<<<dim3(128, 16, 8), dim3(32, 8), 0, stream>>>(x, xthi, xtlo);
    conv_bf16_k<<<2048, 256, 0, stream>>>(x, xbf, (size_t)4194304);
    scale_prep<<<16, 256, 0, stream>>>(ls, sv);

    // 6. per batch: scores GEMM (split-3, K=512) + row softmax -> P
    for (int b = 0; b < 8; ++b) {
        const size_t o = (size_t)b * 4096 * 512;
        gemm_bt<2, true><<<dim3(32, 32, 1), 256, 0, stream>>>(xthi + o, xtlo + o,
            fthi + o, ftlo + o, 512, 512, 4096, nullptr, tt, nullptr, 0, 0, 0, 0);
        softmax_rows<<<4096, 256, 0, stream>>>(tt, sv, pall + (size_t)b * 16777216);
    }

    // 7. GEMM4: pre[b][c][m] = sum_n x[b][c][n] * P[b][m][n]   (plain bf16)
    gemm_bt<3, false><<<dim3(32, 4, 8), 256, 0, stream>>>(xbf, nullptr, pall, nullptr,
        4096, 4096, 4096, nullptr, pre, nullptr, 0,
        (size_t)512 * 4096, (size_t)4096 * 4096, (size_t)512 * 4096);

    // 8. LayerNorm
    ln_rows<<<4096, 256, 0, stream>>>(pre, nw, nb, out);
}

// Round 5
// 2703.016 us; speedup vs baseline: 1.6864x; 1.6864x over previous
//
#include <hip/hip_runtime.h>
#include <stdint.h>

using u16 = unsigned short;
typedef unsigned int u32;
typedef __attribute__((ext_vector_type(4))) float f32x4;
typedef __attribute__((ext_vector_type(8))) short short8;

typedef const __attribute__((address_space(1))) u32* gas_ptr;
typedef __attribute__((address_space(3))) u32* las_ptr;

// ---------- bf16 helpers (bit-level, RNE) ----------
__device__ __forceinline__ u16 f2bf_u(float f) {
    u32 u = __builtin_bit_cast(u32, f);
    u32 r = 0x7fffu + ((u >> 16) & 1u);
    return (u16)((u + r) >> 16);
}
__device__ __forceinline__ float bfu2f(u16 h) {
    u32 u = ((u32)h) << 16;
    return __builtin_bit_cast(float, u);
}
__device__ __forceinline__ void split2(float v, u16& hi, u16& lo) {
    hi = f2bf_u(v);
    lo = f2bf_u(v - bfu2f(hi));   // exact residual, ~16 mantissa bits total
}

__device__ __forceinline__ void gload16(const void* g, void* l) {
    __builtin_amdgcn_global_load_lds((gas_ptr)g, (las_ptr)l, 16, 0, 0);
}

// ---------- GEMM-BT 256x256 tile, BK=32, 8 waves, double-buffered LDS ----------
// C[row][col] = sum_k (Ahi*Bhi + Alo*Bhi + Ahi*Blo)   (SPLIT=true, 3 products)
// Single-barrier pipeline (catalog T3-minimum): per K-tile issue next tile's
// global_load_lds into buf^1, compute 96 MFMA on buf, then one __syncthreads()
// (vmcnt(0)+barrier) -- prefetch latency hides under the MFMA cluster.
// LDS chunk swizzle (proven, 0 conflicts): slot (row,c) holds global chunk
// c ^ ((row>>1)&3); staged via pre-swizzled GLOBAL source (LDS dest linear,
// global_load_lds rule), read with matching XOR.
// Dynamic LDS: SPLIT ? 128 KB : 64 KB (per-(array,buf) region = 8192 u16).
// EPI 0: v=acc+aux[col]; relu; bf16 split write (out0=hi,out1=lo), [M][N]
// EPI 1: v=acc+aux[col]; bf16 split scatter to [b][col][c] (b=row>>9,c=row&511)
// EPI 2: fp32 row-major write (scores; per-row scale applied in softmax)
// EPI 3: fp32 write with batch stride (preLN)
template<int EPI, bool SPLIT>
__global__ __launch_bounds__(512, 2)
void gemm256(const u16* __restrict__ Ah, const u16* __restrict__ Al,
             const u16* __restrict__ Bh, const u16* __restrict__ Bl,
             int K, int lda, int N,
             const float* __restrict__ aux,
             void* __restrict__ out0, void* __restrict__ out1,
             size_t strideA, size_t strideB, size_t strideO)
{
    extern __shared__ __align__(16) u16 lds[];
    u16* const As0 = lds;               // [2][8192]
    u16* const Bs0 = lds + 16384;       // [2][8192]
    u16* const As1 = lds + 32768;       // [2][8192] (SPLIT only)
    u16* const Bs1 = lds + 49152;       // [2][8192] (SPLIT only)

    const int t = threadIdx.x;
    const int w = t >> 6;
    const int l = t & 63;

    // Block swizzle. 16x16 grids: 4x8 region per XCD (assumes dispatch XCD =
    // linear_id % 8; wrong assumption only costs traffic, not correctness).
    // Other grids: generic XCD-chunked bijective swizzle (nwg % 8 == 0).
    int brow, bcol;
    const int gx = gridDim.x, gy = gridDim.y;
    const int orig = blockIdx.y * gx + blockIdx.x;
    if (gx == 16 && gy == 16) {
        const int x = orig & 7, j = orig >> 3;
        brow = ((x & 3) * 4 + (j & 3)) * 256;
        bcol = ((x >> 2) * 8 + (j >> 2)) * 256;
    } else {
        const int nwg = gx * gy;
        const int swz = (orig & 7) * (nwg >> 3) + (orig >> 3);
        brow = (swz / gx) * 256;
        bcol = (swz % gx) * 256;
    }
    const int z = blockIdx.z;

    const u16* A0 = Ah + (size_t)z * strideA;
    const u16* A1 = SPLIT ? (Al + (size_t)z * strideA) : nullptr;
    const u16* B0 = Bh + (size_t)z * strideB;
    const u16* B1 = SPLIT ? (Bl + (size_t)z * strideB) : nullptr;

    // staging: lane l covers row l>>2 (of 16), LDS chunk l&3;
    // global chunk = (l&3) ^ ((row>>1)&3) = (l&3) ^ ((l>>3)&3)  [row base %16==0]
    const int srow = l >> 2;
    const int sca = ((l & 3) ^ ((l >> 3) & 3)) * 8;

    // wave grid 2(M) x 4(N): wave covers rows wr*128..+127, cols wc*64..+63
    const int wr = w >> 2;
    const int wc = w & 3;
    const int lr = l & 15;
    // frag read swizzle: slot chunk = (l>>4) ^ ((row>>1)&3), row%16 = lr
    const int cr = ((l >> 4) ^ ((l >> 1) & 3)) * 8;

    f32x4 acc[8][4];
    const f32x4 zero = {0.f, 0.f, 0.f, 0.f};
#pragma unroll
    for (int i = 0; i < 8; ++i)
#pragma unroll
        for (int j = 0; j < 4; ++j) acc[i][j] = zero;

    const int NT = K >> 5;

    auto STAGE = [&](int buf, int kt) {
        const int kk = kt << 5;
#pragma unroll
        for (int it = 0; it < 2; ++it) {
            const int rbase = it * 128 + w * 16;          // wave-uniform
            const int lo = buf * 8192 + rbase * 32;
            const size_t ga = (size_t)(brow + rbase + srow) * lda + (kk + sca);
            const size_t gb = (size_t)(bcol + rbase + srow) * lda + (kk + sca);
            gload16(A0 + ga, &As0[lo]);
            gload16(B0 + gb, &Bs0[lo]);
            if constexpr (SPLIT) {
                gload16(A1 + ga, &As1[lo]);
                gload16(B1 + gb, &Bs1[lo]);
            }
        }
    };

    STAGE(0, 0);
    __syncthreads();                    // vmcnt(0) + barrier: tile 0 ready
    int cur = 0;

    for (int kt = 0; kt < NT; ++kt) {
        if (kt + 1 < NT) STAGE(cur ^ 1, kt + 1);   // prefetch flies under MFMA
        short8 bh[4], bl[4];
#pragma unroll
        for (int n = 0; n < 4; ++n) {
            const int ro = cur * 8192 + (wc * 64 + n * 16 + lr) * 32 + cr;
            bh[n] = *(const short8*)&Bs0[ro];
            if constexpr (SPLIT) bl[n] = *(const short8*)&Bs1[ro];
        }
#pragma unroll
        for (int mh = 0; mh < 2; ++mh) {
            short8 ah[4], al[4];
#pragma unroll
            for (int m = 0; m < 4; ++m) {
                const int ro = cur * 8192 + (wr * 128 + mh * 64 + m * 16 + lr) * 32 + cr;
                ah[m] = *(const short8*)&As0[ro];
                if constexpr (SPLIT) al[m] = *(const short8*)&As1[ro];
            }
            __builtin_amdgcn_s_setprio(1);
#pragma unroll
            for (int m = 0; m < 4; ++m)
#pragma unroll
                for (int n = 0; n < 4; ++n)
                    acc[mh * 4 + m][n] = __builtin_amdgcn_mfma_f32_16x16x32_bf16(
                        ah[m], bh[n], acc[mh * 4 + m][n], 0, 0, 0);
            if constexpr (SPLIT) {
#pragma unroll
                for (int m = 0; m < 4; ++m)
#pragma unroll
                    for (int n = 0; n < 4; ++n)
                        acc[mh * 4 + m][n] = __builtin_amdgcn_mfma_f32_16x16x32_bf16(
                            al[m], bh[n], acc[mh * 4 + m][n], 0, 0, 0);
#pragma unroll
                for (int m = 0; m < 4; ++m)
#pragma unroll
                    for (int n = 0; n < 4; ++n)
                        acc[mh * 4 + m][n] = __builtin_amdgcn_mfma_f32_16x16x32_bf16(
                            ah[m], bl[n], acc[mh * 4 + m][n], 0, 0, 0);
            }
            __builtin_amdgcn_s_setprio(0);
        }
        __syncthreads();                // vmcnt(0): next tile staged; flip
        cur ^= 1;
    }

#pragma unroll
    for (int mh = 0; mh < 2; ++mh)
#pragma unroll
        for (int m = 0; m < 4; ++m)
#pragma unroll
            for (int n = 0; n < 4; ++n)
#pragma unroll
                for (int j = 0; j < 4; ++j) {
                    const int row = brow + wr * 128 + mh * 64 + m * 16 + (l >> 4) * 4 + j;
                    const int col = bcol + wc * 64 + n * 16 + (l & 15);
                    float v = acc[mh * 4 + m][n][j];
                    if (EPI == 0) {
                        v += aux[col];
                        v = fmaxf(v, 0.f);
                        u16 hi, lo; split2(v, hi, lo);
                        ((u16*)out0)[(size_t)row * N + col] = hi;
                        ((u16*)out1)[(size_t)row * N + col] = lo;
                    } else if (EPI == 1) {
                        v += aux[col];
                        const int bb = row >> 9, cc = row & 511;
                        const size_t idx = ((size_t)bb * N + col) * 512 + cc;
                        u16 hi, lo; split2(v, hi, lo);
                        ((u16*)out0)[idx] = hi;
                        ((u16*)out1)[idx] = lo;
                    } else if (EPI == 2) {
                        ((float*)out0)[(size_t)row * N + col] = v;
                    } else {
                        ((float*)out0)[(size_t)z * strideO + (size_t)row * N + col] = v;
                    }
                }
}

// ---------- elementwise split fp32 -> (hi,lo) bf16 ----------
__global__ void split_k(const float* __restrict__ in, u16* __restrict__ hi,
                        u16* __restrict__ lo, size_t n4)
{
    size_t i = blockIdx.x * (size_t)blockDim.x + threadIdx.x;
    const size_t stride = (size_t)gridDim.x * blockDim.x;
    for (; i < n4; i += stride) {
        const float4 v = ((const float4*)in)[i];
        ushort4 h, l;
        split2(v.x, h.x, l.x);
        split2(v.y, h.y, l.y);
        split2(v.z, h.z, l.z);
        split2(v.w, h.w, l.w);
        ((ushort4*)hi)[i] = h;
        ((ushort4*)lo)[i] = l;
    }
}

// ---------- plain fp32 -> bf16 convert ----------
__global__ void conv_bf16_k(const float* __restrict__ in, u16* __restrict__ out, size_t n4)
{
    size_t i = blockIdx.x * (size_t)blockDim.x + threadIdx.x;
    const size_t stride = (size_t)gridDim.x * blockDim.x;
    for (; i < n4; i += stride) {
        const float4 v = ((const float4*)in)[i];
        ushort4 o;
        o.x = f2bf_u(v.x); o.y = f2bf_u(v.y); o.z = f2bf_u(v.z); o.w = f2bf_u(v.w);
        ((ushort4*)out)[i] = o;
    }
}

// ---------- x (B,512,4096) -> xt (B,4096,512) with bf16 hi/lo split ----------
__global__ void transpose_split_x(const float* __restrict__ x,
                                  u16* __restrict__ xt_hi, u16* __restrict__ xt_lo)
{
    __shared__ float tile[32][33];
    const int b = blockIdx.z;
    const int n0 = blockIdx.x * 32;
    const int c0 = blockIdx.y * 32;
    const int tx = threadIdx.x, ty = threadIdx.y;   // block (32,8)
#pragma unroll
    for (int k = 0; k < 4; ++k)
        tile[ty + 8 * k][tx] = x[((size_t)b * 512 + c0 + ty + 8 * k) * 4096 + n0 + tx];
    __syncthreads();
#pragma unroll
    for (int k = 0; k < 4; ++k) {
        const float v = tile[tx][ty + 8 * k];       // [c_local][n_local]
        u16 hi, lo; split2(v, hi, lo);
        const size_t idx = ((size_t)b * 4096 + n0 + ty + 8 * k) * 512 + c0 + tx;
        xt_hi[idx] = hi;
        xt_lo[idx] = lo;
    }
}

// ---------- scale vector: s[n] = exp(min(ls[n], log(100))) ----------
__global__ void scale_prep(const float* __restrict__ ls, float* __restrict__ s)
{
    const int i = blockIdx.x * blockDim.x + threadIdx.x;
    if (i < 4096) s[i] = expf(fminf(ls[i], 4.605170185988092f));
}

// ---------- row softmax of tempT (4096 cols), row-scale s[m], write bf16 P ----------
__global__ __launch_bounds__(256)
void softmax_rows(const float* __restrict__ T, const float* __restrict__ s, u16* __restrict__ P)
{
    const int m = blockIdx.x;
    const int t = threadIdx.x;
    const float sc = s[m];
    const float* row = T + (size_t)m * 4096;
    float v[16];
    float mx = -3.402823e38f;
#pragma unroll
    for (int i = 0; i < 16; ++i) {
        v[i] = row[t + 256 * i] * sc;
        mx = fmaxf(mx, v[i]);
    }
#pragma unroll
    for (int o = 32; o; o >>= 1) mx = fmaxf(mx, __shfl_xor(mx, o, 64));
    __shared__ float sm[4], ss[4];
    if ((t & 63) == 0) sm[t >> 6] = mx;
    __syncthreads();
    mx = fmaxf(fmaxf(sm[0], sm[1]), fmaxf(sm[2], sm[3]));
    float sum = 0.f;
#pragma unroll
    for (int i = 0; i < 16; ++i) {
        v[i] = expf(v[i] - mx);
        sum += v[i];
    }
#pragma unroll
    for (int o = 32; o; o >>= 1) sum += __shfl_xor(sum, o, 64);
    if ((t & 63) == 0) ss[t >> 6] = sum;
    __syncthreads();
    sum = (ss[0] + ss[1]) + (ss[2] + ss[3]);
    const float inv = 1.f / sum;
#pragma unroll
    for (int i = 0; i < 16; ++i)
        P[(size_t)m * 4096 + t + 256 * i] = f2bf_u(v[i] * inv);
}

// ---------- LayerNorm rows of 4096 ----------
__global__ __launch_bounds__(256)
void ln_rows(const float* __restrict__ X, const float* __restrict__ gw,
             const float* __restrict__ gb, float* __restrict__ out)
{
    const int r = blockIdx.x;
    const int t = threadIdx.x;
    const float* row = X + (size_t)r * 4096;
    float v[16];
    float s1 = 0.f, s2 = 0.f;
#pragma unroll
    for (int i = 0; i < 16; ++i) {
        v[i] = row[t + 256 * i];
        s1 += v[i];
        s2 += v[i] * v[i];
    }
#pragma unroll
    for (int o = 32; o; o >>= 1) {
        s1 += __shfl_xor(s1, o, 64);
        s2 += __shfl_xor(s2, o, 64);
    }
    __shared__ float m1[4], m2[4];
    if ((t & 63) == 0) { m1[t >> 6] = s1; m2[t >> 6] = s2; }
    __syncthreads();
    s1 = (m1[0] + m1[1]) + (m1[2] + m1[3]);
    s2 = (m2[0] + m2[1]) + (m2[2] + m2[3]);
    const float mu = s1 * (1.f / 4096.f);
    const float var = s2 * (1.f / 4096.f) - mu * mu;
    const float rs = rsqrtf(var + 1e-5f);
#pragma unroll
    for (int i = 0; i < 16; ++i) {
        const int n = t + 256 * i;
        out[(size_t)r * 4096 + n] = (v[i] - mu) * rs * gw[n] + gb[n];
    }
}

extern "C" void kernel_launch(void* const* d_in, const int* in_sizes, int n_in,
                              void* d_out, int out_size, void* d_ws, size_t ws_size,
                              hipStream_t stream)
{
    const float* x  = (const float*)d_in[0];
    const float* fe = (const float*)d_in[1];
    const float* w1 = (const float*)d_in[2];
    const float* b1 = (const float*)d_in[3];
    const float* w2 = (const float*)d_in[4];
    const float* b2 = (const float*)d_in[5];
    const float* ls = (const float*)d_in[6];
    const float* nw = (const float*)d_in[7];
    const float* nb = (const float*)d_in[8];
    float* out = (float*)d_out;
    char* ws = (char*)d_ws;

    if (ws_size < 637550592ull) return;

    // Allow 128 KB dynamic LDS for the split GEMM instantiations (64 KB ones
    // are under the default cap anyway). Host-side attribute set, not a
    // stream op -- graph-capture safe.
    static_assert(sizeof(void*) == 8, "");
    hipFuncSetAttribute((const void*)gemm256<0, true>,
                        hipFuncAttributeMaxDynamicSharedMemorySize, 131072);
    hipFuncSetAttribute((const void*)gemm256<1, true>,
                        hipFuncAttributeMaxDynamicSharedMemorySize, 131072);
    hipFuncSetAttribute((const void*)gemm256<2, true>,
                        hipFuncAttributeMaxDynamicSharedMemorySize, 131072);

    // Workspace plan (stream-order lifetime reuse):
    u16*  fhi  = (u16*) (ws + 0ull);
    u16*  flo  = (u16*) (ws + 134217728ull);
    u16*  w1hi = (u16*) (ws + 268435456ull);
    u16*  w1lo = (u16*) (ws + 402653184ull);
    u16*  hhi  = (u16*) (ws + 536870912ull);
    u16*  hlo  = (u16*) (ws + 570425344ull);
    u16*  w2hi = (u16*) (ws + 0ull);           // fe region dead after GEMM1
    u16*  w2lo = (u16*) (ws + 33554432ull);
    u16*  fthi = (u16*) (ws + 67108864ull);
    u16*  ftlo = (u16*) (ws + 100663296ull);
    u16*  xthi = (u16*) (ws + 134217728ull);
    u16*  xtlo = (u16*) (ws + 167772160ull);
    u16*  xbf  = (u16*) (ws + 201326592ull);
    float* tt  = (float*)(ws + 234881024ull);   // one-batch scores, fp32
    u16*  pall = (u16*) (ws + 301989888ull);    // P bf16, all batches
    float* pre = (float*)(ws + 570425344ull);   // pre-LN fp32 (h dead)
    float* sv  = (float*)(ws + 637534208ull);

    // 1. split feature and fc1_w
    split_k<<<2048, 256, 0, stream>>>(fe, fhi, flo, (size_t)16777216);
    split_k<<<2048, 256, 0, stream>>>(w1, w1hi, w1lo, (size_t)16777216);

    // 2. GEMM1: h = relu(feature @ fc1_w^T + b1), split-3, 256-blocks all-resident
    gemm256<0, true><<<dim3(16, 16, 1), 512, 131072, stream>>>(
        fhi, flo, w1hi, w1lo, 16384, 16384, 4096, b1, hhi, hlo, 0, 0, 0);

    // 3. split fc2_w (fe region dead after GEMM1 in stream order)
    split_k<<<2048, 256, 0, stream>>>(w2, w2hi, w2lo, (size_t)4194304);

    // 4. GEMM2: feat = h @ fc2_w^T + b2, split scatter to ft[b][n][c]
    gemm256<1, true><<<dim3(16, 16, 1), 512, 131072, stream>>>(
        hhi, hlo, w2hi, w2lo, 4096, 4096, 4096, b2, fthi, ftlo, 0, 0, 0);

    // 5. x transforms + scale vector
    transpose_split_x<<<dim3(128, 16, 8), dim3(32, 8), 0, stream>>>(x, xthi, xtlo);
    conv_bf16_k<<<2048, 256, 0, stream>>>(x, xbf, (size_t)4194304);
    scale_prep<<<16, 256, 0, stream>>>(ls, sv);

    // 6. per batch: scores GEMM (split-3, K=512) + row softmax -> P
    for (int b = 0; b < 8; ++b) {
        const size_t o = (size_t)b * 4096 * 512;
        gemm256<2, true><<<dim3(16, 16, 1), 512, 131072, stream>>>(
            xthi + o, xtlo + o, fthi + o, ftlo + o, 512, 512, 4096,
            nullptr, tt, nullptr, 0, 0, 0);
        softmax_rows<<<4096, 256, 0, stream>>>(tt, sv, pall + (size_t)b * 16777216);
    }

    // 7. GEMM4: pre[b][c][m] = sum_n x[b][c][n] * P[b][m][n]   (plain bf16)
    gemm256<3, false><<<dim3(16, 2, 8), 512, 65536, stream>>>(
        xbf, nullptr, pall, nullptr, 4096, 4096, 4096, nullptr, pre, nullptr,
        (size_t)512 * 4096, (size_t)4096 * 4096, (size_t)512 * 4096);

    // 8. LayerNorm
    ln_rows<<<4096, 256, 0, stream>>>(pre, nw, nb, out);
}

// Round 6
// 2690.818 us; speedup vs baseline: 1.6940x; 1.0045x over previous
//
#include <hip/hip_runtime.h>
#include <stdint.h>

using u16 = unsigned short;
typedef unsigned int u32;
typedef __attribute__((ext_vector_type(4))) float f32x4;
typedef __attribute__((ext_vector_type(8))) short short8;

typedef const __attribute__((address_space(1))) u32* gas_ptr;
typedef __attribute__((address_space(3))) u32* las_ptr;

// ---------- bf16 helpers (bit-level, RNE) ----------
__device__ __forceinline__ u16 f2bf_u(float f) {
    u32 u = __builtin_bit_cast(u32, f);
    u32 r = 0x7fffu + ((u >> 16) & 1u);
    return (u16)((u + r) >> 16);
}
__device__ __forceinline__ float bfu2f(u16 h) {
    u32 u = ((u32)h) << 16;
    return __builtin_bit_cast(float, u);
}
__device__ __forceinline__ void split2(float v, u16& hi, u16& lo) {
    hi = f2bf_u(v);
    lo = f2bf_u(v - bfu2f(hi));   // exact residual, ~16 mantissa bits total
}

__device__ __forceinline__ void gload16(const void* g, void* l) {
    __builtin_amdgcn_global_load_lds((gas_ptr)g, (las_ptr)l, 16, 0, 0);
}

// ---------- GEMM-BT 256x256 tile, BK=32, 8 waves ----------
// Never-drain counted-vmcnt pipeline (catalog T3+T4), depth-2 tile prefetch:
//   LDS: 3 buffers x {Ahi, Bhi, (Alo)} (SPLIT: 144 KB, else 96 KB).
//   Blo lives in per-wave REGISTER fragments (wave-private B-frag; direct
//   global loads, 16 rows x 64B per inst -> full-line sectors, L2/L3-cached).
//   Per K-tile: s_waitcnt vmcnt(10|4) [tile kt's group done; tile kt+1's
//   group of 10|4 stays in flight] -> s_barrier -> STAGE(kt+2) -> 96 MFMA
//   -> BLOQ-refill(kt+2). vmcnt never drains to 0 in the main loop.
// Group order ledger (SPLIT): per tile t: [S(t): 6 gload_lds][Q(t): 4 reg
//   loads]; at phase t top, ops newer than Q(t) = S(t+1)+Q(t+1) = 10.
//   Tail: phase NT-1 waits vmcnt(0). Non-split: groups of 4, wait vmcnt(4).
// LDS chunk swizzle (proven, 0 conflicts): slot (row,c) holds global chunk
// c ^ ((row>>1)&3); staged via pre-swizzled GLOBAL source, read with XOR.
// EPI 0: v=acc+aux[col]; relu; bf16 split write (out0=hi,out1=lo), [M][N]
// EPI 1: v=acc+aux[col]; bf16 split scatter to [b][col][c] (b=row>>9,c=row&511)
// EPI 2: fp32 row-major write (scores; per-row scale applied in softmax)
// EPI 3: fp32 write with batch stride (preLN)

#define STAGE(CBUF, KT)                                                      \
  {                                                                          \
    const int kk_ = (KT) << 5;                                               \
    _Pragma("unroll")                                                        \
    for (int it_ = 0; it_ < 2; ++it_) {                                      \
      const int rb_ = it_ * 128 + w * 16;                                    \
      const int lo_ = (CBUF) * 8192 + rb_ * 32;                              \
      const size_t ga_ = (size_t)(brow + rb_ + srow) * lda + (kk_ + sca);    \
      const size_t gb_ = (size_t)(bcol + rb_ + srow) * lda + (kk_ + sca);    \
      gload16(A0 + ga_, &As0[lo_]);                                          \
      gload16(B0 + gb_, &Bs0[lo_]);                                          \
      if constexpr (SPLIT) gload16(A1 + ga_, &As1[lo_]);                     \
    }                                                                        \
  }

#define BLOQ(Q, KT)                                                          \
  {                                                                          \
    const u16* bb_ = B1 + (size_t)(bcol + wc * 64 + lr) * lda                \
                     + (((KT) << 5) + ((l >> 4) * 8));                       \
    _Pragma("unroll")                                                        \
    for (int n_ = 0; n_ < 4; ++n_)                                           \
      Q[n_] = *(const short8*)(bb_ + (size_t)(n_ * 16) * lda);               \
  }

#define PHASE(KT, CBUF, Q)                                                   \
  {                                                                          \
    if ((KT) == NT - 1) {                                                    \
      asm volatile("s_waitcnt vmcnt(0)" ::: "memory");                       \
    } else {                                                                 \
      if constexpr (SPLIT) asm volatile("s_waitcnt vmcnt(10)" ::: "memory"); \
      else asm volatile("s_waitcnt vmcnt(4)" ::: "memory");                  \
    }                                                                        \
    __builtin_amdgcn_s_barrier();                                            \
    __builtin_amdgcn_sched_barrier(0);                                       \
    {                                                                        \
      int cs_ = (CBUF) + 2; if (cs_ >= 3) cs_ -= 3;                          \
      if ((KT) + 2 < NT) STAGE(cs_, (KT) + 2);                               \
    }                                                                        \
    short8 bh_[4];                                                           \
    _Pragma("unroll")                                                        \
    for (int n_ = 0; n_ < 4; ++n_)                                           \
      bh_[n_] = *(const short8*)&Bs0[(CBUF) * 8192 +                         \
                                     (wc * 64 + n_ * 16 + lr) * 32 + cr];    \
    _Pragma("unroll")                                                        \
    for (int mh_ = 0; mh_ < 2; ++mh_) {                                      \
      short8 ah_[4], al_[4];                                                 \
      _Pragma("unroll")                                                      \
      for (int m_ = 0; m_ < 4; ++m_) {                                       \
        const int ro_ = (CBUF) * 8192 +                                      \
                        (wr * 128 + mh_ * 64 + m_ * 16 + lr) * 32 + cr;      \
        ah_[m_] = *(const short8*)&As0[ro_];                                 \
        if constexpr (SPLIT) al_[m_] = *(const short8*)&As1[ro_];            \
      }                                                                      \
      __builtin_amdgcn_s_setprio(1);                                         \
      _Pragma("unroll")                                                      \
      for (int m_ = 0; m_ < 4; ++m_)                                         \
        _Pragma("unroll")                                                    \
        for (int n_ = 0; n_ < 4; ++n_)                                       \
          acc[mh_ * 4 + m_][n_] = __builtin_amdgcn_mfma_f32_16x16x32_bf16(   \
              ah_[m_], bh_[n_], acc[mh_ * 4 + m_][n_], 0, 0, 0);             \
      if constexpr (SPLIT) {                                                 \
        _Pragma("unroll")                                                    \
        for (int m_ = 0; m_ < 4; ++m_)                                       \
          _Pragma("unroll")                                                  \
          for (int n_ = 0; n_ < 4; ++n_)                                     \
            acc[mh_ * 4 + m_][n_] = __builtin_amdgcn_mfma_f32_16x16x32_bf16( \
                al_[m_], bh_[n_], acc[mh_ * 4 + m_][n_], 0, 0, 0);           \
        _Pragma("unroll")                                                    \
        for (int m_ = 0; m_ < 4; ++m_)                                       \
          _Pragma("unroll")                                                  \
          for (int n_ = 0; n_ < 4; ++n_)                                     \
            acc[mh_ * 4 + m_][n_] = __builtin_amdgcn_mfma_f32_16x16x32_bf16( \
                ah_[m_], Q[n_], acc[mh_ * 4 + m_][n_], 0, 0, 0);             \
      }                                                                      \
      __builtin_amdgcn_s_setprio(0);                                         \
    }                                                                        \
    __builtin_amdgcn_sched_barrier(0);                                       \
    if ((KT) + 2 < NT) {                                                     \
      if constexpr (SPLIT) BLOQ(Q, (KT) + 2);                                \
    }                                                                        \
    __builtin_amdgcn_sched_barrier(0);                                       \
  }

template<int EPI, bool SPLIT>
__global__ __launch_bounds__(512, 2)
void gemm256(const u16* __restrict__ Ah, const u16* __restrict__ Al,
             const u16* __restrict__ Bh, const u16* __restrict__ Bl,
             int K, int lda, int N,
             const float* __restrict__ aux,
             void* __restrict__ out0, void* __restrict__ out1,
             size_t strideA, size_t strideB, size_t strideO)
{
    extern __shared__ __align__(16) u16 lds[];
    u16* const As0 = lds;                                   // [3][8192]
    u16* const Bs0 = lds + 3 * 8192;                        // [3][8192]
    u16* const As1 = SPLIT ? (lds + 6 * 8192) : lds;        // [3][8192]

    const int t = threadIdx.x;
    const int w = t >> 6;
    const int l = t & 63;

    // Block swizzle. 16x16 grids: 4x8 region per XCD; other grids: generic
    // XCD-chunked bijective swizzle (nwg % 8 == 0).
    int brow, bcol;
    const int gx = gridDim.x, gy = gridDim.y;
    const int orig = blockIdx.y * gx + blockIdx.x;
    if (gx == 16 && gy == 16) {
        const int x = orig & 7, j = orig >> 3;
        brow = ((x & 3) * 4 + (j & 3)) * 256;
        bcol = ((x >> 2) * 8 + (j >> 2)) * 256;
    } else {
        const int nwg = gx * gy;
        const int swz = (orig & 7) * (nwg >> 3) + (orig >> 3);
        brow = (swz / gx) * 256;
        bcol = (swz % gx) * 256;
    }
    const int z = blockIdx.z;

    const u16* A0 = Ah + (size_t)z * strideA;
    const u16* A1 = SPLIT ? (Al + (size_t)z * strideA) : nullptr;
    const u16* B0 = Bh + (size_t)z * strideB;
    const u16* B1 = SPLIT ? (Bl + (size_t)z * strideB) : nullptr;

    // staging: lane l covers row l>>2 (of 16), LDS chunk l&3;
    // global chunk = (l&3) ^ ((row>>1)&3) = (l&3) ^ ((l>>3)&3)
    const int srow = l >> 2;
    const int sca = ((l & 3) ^ ((l >> 3) & 3)) * 8;

    // wave grid 2(M) x 4(N)
    const int wr = w >> 2;
    const int wc = w & 3;
    const int lr = l & 15;
    // frag read swizzle: slot chunk = (l>>4) ^ ((row>>1)&3), row%16 = lr
    const int cr = ((l >> 4) ^ ((l >> 1) & 3)) * 8;

    f32x4 acc[8][4];
    const f32x4 zero = {0.f, 0.f, 0.f, 0.f};
#pragma unroll
    for (int i = 0; i < 8; ++i)
#pragma unroll
        for (int j = 0; j < 4; ++j) acc[i][j] = zero;

    const int NT = K >> 5;
    short8 qA[4], qB[4];

    // prologue: stage tiles 0 and 1 (groups [S0,Q0,S1,Q1])
    STAGE(0, 0);
    if constexpr (SPLIT) BLOQ(qA, 0);
    STAGE(1, 1);
    if constexpr (SPLIT) BLOQ(qB, 1);

    int c = 0;
    for (int kt = 0; kt < NT; kt += 2) {
        PHASE(kt, c, qA);
        c = (c == 2) ? 0 : c + 1;
        PHASE(kt + 1, c, qB);
        c = (c == 2) ? 0 : c + 1;
    }

#pragma unroll
    for (int mh = 0; mh < 2; ++mh)
#pragma unroll
        for (int m = 0; m < 4; ++m)
#pragma unroll
            for (int n = 0; n < 4; ++n)
#pragma unroll
                for (int j = 0; j < 4; ++j) {
                    const int row = brow + wr * 128 + mh * 64 + m * 16 + (l >> 4) * 4 + j;
                    const int col = bcol + wc * 64 + n * 16 + (l & 15);
                    float v = acc[mh * 4 + m][n][j];
                    if (EPI == 0) {
                        v += aux[col];
                        v = fmaxf(v, 0.f);
                        u16 hi, lo; split2(v, hi, lo);
                        ((u16*)out0)[(size_t)row * N + col] = hi;
                        ((u16*)out1)[(size_t)row * N + col] = lo;
                    } else if (EPI == 1) {
                        v += aux[col];
                        const int bb = row >> 9, cc = row & 511;
                        const size_t idx = ((size_t)bb * N + col) * 512 + cc;
                        u16 hi, lo; split2(v, hi, lo);
                        ((u16*)out0)[idx] = hi;
                        ((u16*)out1)[idx] = lo;
                    } else if (EPI == 2) {
                        ((float*)out0)[(size_t)row * N + col] = v;
                    } else {
                        ((float*)out0)[(size_t)z * strideO + (size_t)row * N + col] = v;
                    }
                }
}

// ---------- elementwise split fp32 -> (hi,lo) bf16 ----------
__global__ void split_k(const float* __restrict__ in, u16* __restrict__ hi,
                        u16* __restrict__ lo, size_t n4)
{
    size_t i = blockIdx.x * (size_t)blockDim.x + threadIdx.x;
    const size_t stride = (size_t)gridDim.x * blockDim.x;
    for (; i < n4; i += stride) {
        const float4 v = ((const float4*)in)[i];
        ushort4 h, l;
        split2(v.x, h.x, l.x);
        split2(v.y, h.y, l.y);
        split2(v.z, h.z, l.z);
        split2(v.w, h.w, l.w);
        ((ushort4*)hi)[i] = h;
        ((ushort4*)lo)[i] = l;
    }
}

// ---------- plain fp32 -> bf16 convert ----------
__global__ void conv_bf16_k(const float* __restrict__ in, u16* __restrict__ out, size_t n4)
{
    size_t i = blockIdx.x * (size_t)blockDim.x + threadIdx.x;
    const size_t stride = (size_t)gridDim.x * blockDim.x;
    for (; i < n4; i += stride) {
        const float4 v = ((const float4*)in)[i];
        ushort4 o;
        o.x = f2bf_u(v.x); o.y = f2bf_u(v.y); o.z = f2bf_u(v.z); o.w = f2bf_u(v.w);
        ((ushort4*)out)[i] = o;
    }
}

// ---------- x (B,512,4096) -> xt (B,4096,512) with bf16 hi/lo split ----------
__global__ void transpose_split_x(const float* __restrict__ x,
                                  u16* __restrict__ xt_hi, u16* __restrict__ xt_lo)
{
    __shared__ float tile[32][33];
    const int b = blockIdx.z;
    const int n0 = blockIdx.x * 32;
    const int c0 = blockIdx.y * 32;
    const int tx = threadIdx.x, ty = threadIdx.y;   // block (32,8)
#pragma unroll
    for (int k = 0; k < 4; ++k)
        tile[ty + 8 * k][tx] = x[((size_t)b * 512 + c0 + ty + 8 * k) * 4096 + n0 + tx];
    __syncthreads();
#pragma unroll
    for (int k = 0; k < 4; ++k) {
        const float v = tile[tx][ty + 8 * k];       // [c_local][n_local]
        u16 hi, lo; split2(v, hi, lo);
        const size_t idx = ((size_t)b * 4096 + n0 + ty + 8 * k) * 512 + c0 + tx;
        xt_hi[idx] = hi;
        xt_lo[idx] = lo;
    }
}

// ---------- scale vector: s[n] = exp(min(ls[n], log(100))) ----------
__global__ void scale_prep(const float* __restrict__ ls, float* __restrict__ s)
{
    const int i = blockIdx.x * blockDim.x + threadIdx.x;
    if (i < 4096) s[i] = expf(fminf(ls[i], 4.605170185988092f));
}

// ---------- row softmax of tempT (4096 cols), row-scale s[m], write bf16 P ----------
__global__ __launch_bounds__(256)
void softmax_rows(const float* __restrict__ T, const float* __restrict__ s, u16* __restrict__ P)
{
    const int m = blockIdx.x;
    const int t = threadIdx.x;
    const float sc = s[m];
    const float* row = T + (size_t)m * 4096;
    float v[16];
    float mx = -3.402823e38f;
#pragma unroll
    for (int i = 0; i < 16; ++i) {
        v[i] = row[t + 256 * i] * sc;
        mx = fmaxf(mx, v[i]);
    }
#pragma unroll
    for (int o = 32; o; o >>= 1) mx = fmaxf(mx, __shfl_xor(mx, o, 64));
    __shared__ float sm[4], ss[4];
    if ((t & 63) == 0) sm[t >> 6] = mx;
    __syncthreads();
    mx = fmaxf(fmaxf(sm[0], sm[1]), fmaxf(sm[2], sm[3]));
    float sum = 0.f;
#pragma unroll
    for (int i = 0; i < 16; ++i) {
        v[i] = expf(v[i] - mx);
        sum += v[i];
    }
#pragma unroll
    for (int o = 32; o; o >>= 1) sum += __shfl_xor(sum, o, 64);
    if ((t & 63) == 0) ss[t >> 6] = sum;
    __syncthreads();
    sum = (ss[0] + ss[1]) + (ss[2] + ss[3]);
    const float inv = 1.f / sum;
#pragma unroll
    for (int i = 0; i < 16; ++i)
        P[(size_t)m * 4096 + t + 256 * i] = f2bf_u(v[i] * inv);
}

// ---------- LayerNorm rows of 4096 ----------
__global__ __launch_bounds__(256)
void ln_rows(const float* __restrict__ X, const float* __restrict__ gw,
             const float* __restrict__ gb, float* __restrict__ out)
{
    const int r = blockIdx.x;
    const int t = threadIdx.x;
    const float* row = X + (size_t)r * 4096;
    float v[16];
    float s1 = 0.f, s2 = 0.f;
#pragma unroll
    for (int i = 0; i < 16; ++i) {
        v[i] = row[t + 256 * i];
        s1 += v[i];
        s2 += v[i] * v[i];
    }
#pragma unroll
    for (int o = 32; o; o >>= 1) {
        s1 += __shfl_xor(s1, o, 64);
        s2 += __shfl_xor(s2, o, 64);
    }
    __shared__ float m1[4], m2[4];
    if ((t & 63) == 0) { m1[t >> 6] = s1; m2[t >> 6] = s2; }
    __syncthreads();
    s1 = (m1[0] + m1[1]) + (m1[2] + m1[3]);
    s2 = (m2[0] + m2[1]) + (m2[2] + m2[3]);
    const float mu = s1 * (1.f / 4096.f);
    const float var = s2 * (1.f / 4096.f) - mu * mu;
    const float rs = rsqrtf(var + 1e-5f);
#pragma unroll
    for (int i = 0; i < 16; ++i) {
        const int n = t + 256 * i;
        out[(size_t)r * 4096 + n] = (v[i] - mu) * rs * gw[n] + gb[n];
    }
}

extern "C" void kernel_launch(void* const* d_in, const int* in_sizes, int n_in,
                              void* d_out, int out_size, void* d_ws, size_t ws_size,
                              hipStream_t stream)
{
    const float* x  = (const float*)d_in[0];
    const float* fe = (const float*)d_in[1];
    const float* w1 = (const float*)d_in[2];
    const float* b1 = (const float*)d_in[3];
    const float* w2 = (const float*)d_in[4];
    const float* b2 = (const float*)d_in[5];
    const float* ls = (const float*)d_in[6];
    const float* nw = (const float*)d_in[7];
    const float* nb = (const float*)d_in[8];
    float* out = (float*)d_out;
    char* ws = (char*)d_ws;

    if (ws_size < 637550592ull) return;

    // Dynamic-LDS caps (host-side attribute, graph-capture safe).
    hipFuncSetAttribute((const void*)gemm256<0, true>,
                        hipFuncAttributeMaxDynamicSharedMemorySize, 147456);
    hipFuncSetAttribute((const void*)gemm256<1, true>,
                        hipFuncAttributeMaxDynamicSharedMemorySize, 147456);
    hipFuncSetAttribute((const void*)gemm256<2, true>,
                        hipFuncAttributeMaxDynamicSharedMemorySize, 147456);
    hipFuncSetAttribute((const void*)gemm256<3, false>,
                        hipFuncAttributeMaxDynamicSharedMemorySize, 98304);

    // Workspace plan (stream-order lifetime reuse):
    u16*  fhi  = (u16*) (ws + 0ull);
    u16*  flo  = (u16*) (ws + 134217728ull);
    u16*  w1hi = (u16*) (ws + 268435456ull);
    u16*  w1lo = (u16*) (ws + 402653184ull);
    u16*  hhi  = (u16*) (ws + 536870912ull);
    u16*  hlo  = (u16*) (ws + 570425344ull);
    u16*  w2hi = (u16*) (ws + 0ull);           // fe region dead after GEMM1
    u16*  w2lo = (u16*) (ws + 33554432ull);
    u16*  fthi = (u16*) (ws + 67108864ull);
    u16*  ftlo = (u16*) (ws + 100663296ull);
    u16*  xthi = (u16*) (ws + 134217728ull);
    u16*  xtlo = (u16*) (ws + 167772160ull);
    u16*  xbf  = (u16*) (ws + 201326592ull);
    float* tt  = (float*)(ws + 234881024ull);   // one-batch scores, fp32
    u16*  pall = (u16*) (ws + 301989888ull);    // P bf16, all batches
    float* pre = (float*)(ws + 570425344ull);   // pre-LN fp32 (h dead)
    float* sv  = (float*)(ws + 637534208ull);

    // 1. split feature and fc1_w
    split_k<<<2048, 256, 0, stream>>>(fe, fhi, flo, (size_t)16777216);
    split_k<<<2048, 256, 0, stream>>>(w1, w1hi, w1lo, (size_t)16777216);

    // 2. GEMM1: h = relu(feature @ fc1_w^T + b1), split-3, counted-vmcnt pipe
    gemm256<0, true><<<dim3(16, 16, 1), 512, 147456, stream>>>(
        fhi, flo, w1hi, w1lo, 16384, 16384, 4096, b1, hhi, hlo, 0, 0, 0);

    // 3. split fc2_w (fe region dead after GEMM1 in stream order)
    split_k<<<2048, 256, 0, stream>>>(w2, w2hi, w2lo, (size_t)4194304);

    // 4. GEMM2: feat = h @ fc2_w^T + b2, split scatter to ft[b][n][c]
    gemm256<1, true><<<dim3(16, 16, 1), 512, 147456, stream>>>(
        hhi, hlo, w2hi, w2lo, 4096, 4096, 4096, b2, fthi, ftlo, 0, 0, 0);

    // 5. x transforms + scale vector
    transpose_split_x<<<dim3(128, 16, 8), dim3(32, 8), 0, stream>>>(x, xthi, xtlo);
    conv_bf16_k<<<2048, 256, 0, stream>>>(x, xbf, (size_t)4194304);
    scale_prep<<<16, 256, 0, stream>>>(ls, sv);

    // 6. per batch: scores GEMM (split-3, K=512) + row softmax -> P
    for (int b = 0; b < 8; ++b) {
        const size_t o = (size_t)b * 4096 * 512;
        gemm256<2, true><<<dim3(16, 16, 1), 512, 147456, stream>>>(
            xthi + o, xtlo + o, fthi + o, ftlo + o, 512, 512, 4096,
            nullptr, tt, nullptr, 0, 0, 0);
        softmax_rows<<<4096, 256, 0, stream>>>(tt, sv, pall + (size_t)b * 16777216);
    }

    // 7. GEMM4: pre[b][c][m] = sum_n x[b][c][n] * P[b][m][n]   (plain bf16)
    gemm256<3, false><<<dim3(16, 2, 8), 512, 98304, stream>>>(
        xbf, nullptr, pall, nullptr, 4096, 4096, 4096, nullptr, pre, nullptr,
        (size_t)512 * 4096, (size_t)4096 * 4096, (size_t)512 * 4096);

    // 8. LayerNorm
    ln_rows<<<4096, 256, 0, stream>>>(pre, nw, nb, out);
}